// Round 2
// baseline (235.504 us; speedup 1.0000x reference)
//
#include <hip/hip_runtime.h>

#define NN   4096
#define KNBR 8
#define DF   240
#define SUBW 8    // candidate sub-ranges (waves) per kNN block
#define QPB  64   // queries per kNN block
#define NQRT 4    // candidate quarters

// Distance-only sorted-top-8 insert: pure med3/min chain, NO masks, NO bools.
__device__ __forceinline__ void insD(float v, float t[KNBR]) {
#pragma unroll
  for (int k = KNBR - 1; k >= 1; k--)
    t[k] = __builtin_amdgcn_fmed3f(t[k - 1], t[k], v);
  t[0] = fminf(t[0], v);
}

// (distance,index) sorted-top-8 insert — proven formulation (VGPR 24):
__device__ __forceinline__ void insertDI(float d2, int j, float bd[KNBR],
                                         int bi[KNBR]) {
#pragma unroll
  for (int k = KNBR - 1; k >= 1; k--) {
    bool mk  = d2 < bd[k];
    bool mk1 = d2 < bd[k - 1];
    bd[k] = mk ? (mk1 ? bd[k - 1] : d2) : bd[k];
    bi[k] = mk ? (mk1 ? bi[k - 1] : j) : bi[k];
  }
  bool m0 = d2 < bd[0];
  bd[0] = m0 ? d2 : bd[0];
  bi[0] = m0 ? j : bi[0];
}

// ---------------------------------------------------------------------------
// Kernel 1: kNN distance scan (pass 1) ⊕ weight fusion.
//   blocks [0,1024): per-(query,quarter) sorted top-8 DISTANCES -> qd.
//   blocks [1024,1034): fuse weights (5120 outputs, 512 threads/block):
//     WA = sA*(W2@L0) 32x64 | WB = sB*(W1@L1) 64x32
//     WC = sC*(W4@L1) 16x32 | WD = sD*(W3@L2) 32x16
// ---------------------------------------------------------------------------
__global__ __launch_bounds__(512) void knn_scan_fuse(
    const float* __restrict__ coords, float* __restrict__ qd,
    const float* __restrict__ W1, const float* __restrict__ W2,
    const float* __restrict__ W3, const float* __restrict__ W4,
    const float* __restrict__ L0, const float* __restrict__ L1,
    const float* __restrict__ L2, float* __restrict__ Wf) {
  if (blockIdx.x >= 1024) {            // -------- weight-fusion blocks
    const float sA = 0.012757759076995719f;  // sqrt(1/96)/8
    const float sB = 0.019764235376052370f;  // 1/sqrt(80*32)
    const float sC = 0.034232659844072875f;  // sqrt(3)/sqrt(80*32)
    const float sD = 0.098821176880261850f;  // sqrt(5/32)/4
    int idx = (blockIdx.x - 1024) * 512 + threadIdx.x;  // [0,5120)
    if (idx < 2048) {                       // WA: W2(32x64) @ L0(64x64)
      int u = idx >> 6, c = idx & 63;
      float a = 0.f;
#pragma unroll 8
      for (int m = 0; m < 64; m++) a += W2[u * 64 + m] * L0[m * 64 + c];
      Wf[idx] = sA * a;
    } else if (idx < 4096) {                // WB: W1(64x32) @ L1(32x32)
      int t = idx - 2048;
      int u = t >> 5, c = t & 31;
      float a = 0.f;
#pragma unroll 8
      for (int m = 0; m < 32; m++) a += W1[u * 32 + m] * L1[m * 32 + c];
      Wf[idx] = sB * a;
    } else if (idx < 4608) {                // WC: W4(16x32) @ L1(32x32)
      int t = idx - 4096;
      int u = t >> 5, c = t & 31;
      float a = 0.f;
#pragma unroll 8
      for (int m = 0; m < 32; m++) a += W4[u * 32 + m] * L1[m * 32 + c];
      Wf[idx] = sC * a;
    } else {                                // WD: W3(32x16) @ L2(16x16)
      int t = idx - 4608;
      int u = t >> 4, c = t & 15;
      float a = 0.f;
#pragma unroll 8
      for (int m = 0; m < 16; m++) a += W3[u * 16 + m] * L2[m * 16 + c];
      Wf[idx] = sD * a;
    }
    return;
  }

  // -------- distance-scan blocks (unchanged, verified hot loop)
  __shared__ float pd[SUBW][QPB][KNBR + 1];        // stride-9 pad
  const int blk = blockIdx.x;
  const int b = blk >> 8;
  const int chunk = (blk >> 2) & 63;
  const int quarter = blk & 3;
  const int qi  = threadIdx.x & 63;
  const int sub = threadIdx.x >> 6;
  const int iq  = chunk * 64 + qi;
  const float* cb = coords + (size_t)b * NN * 3;
  const float qx = cb[iq * 3 + 0], qy = cb[iq * 3 + 1], qz = cb[iq * 3 + 2];
  float td[KNBR];
#pragma unroll
  for (int k = 0; k < KNBR; k++) td[k] = 3.0e38f;
  const int j0 = quarter * (NN / NQRT) + sub * 128;
  const float* cp = cb + (size_t)j0 * 3;
#pragma unroll 4
  for (int it = 0; it < 128; ++it) {
    float dx = cp[it * 3 + 0] - qx;
    float dy = cp[it * 3 + 1] - qy;
    float dz = cp[it * 3 + 2] - qz;
    float d2 = dx * dx + dy * dy + dz * dz;
    d2 = (j0 + it == iq) ? 3.0e38f : d2;   // exclude self
    insD(d2, td);
  }
#pragma unroll
  for (int k = 0; k < KNBR; k++) pd[sub][qi][k] = td[k];
  __syncthreads();
  if (threadIdx.x < 64) {
    float md[KNBR];
#pragma unroll
    for (int k = 0; k < KNBR; k++) md[k] = 3.0e38f;
    for (int s = 0; s < SUBW; s++) {
#pragma unroll
      for (int k = 0; k < KNBR; k++) insD(pd[s][qi][k], md);
    }
    size_t base = ((size_t)(b * NN + iq) * NQRT + quarter) * KNBR;
#pragma unroll
    for (int k = 0; k < KNBR; k++) qd[base + k] = md[k];
  }
}

// ---------------------------------------------------------------------------
// Kernel 2: per-query threshold = global 8th-smallest distance.
// ---------------------------------------------------------------------------
__global__ __launch_bounds__(256) void knn_thr(
    const float* __restrict__ qd, float* __restrict__ thr) {
  int g = blockIdx.x * 256 + threadIdx.x;   // global query id
  float md[KNBR];
#pragma unroll
  for (int k = 0; k < KNBR; k++) md[k] = 3.0e38f;
  size_t base = (size_t)g * NQRT * KNBR;
#pragma unroll
  for (int i = 0; i < NQRT * KNBR; i++) insD(qd[base + i], md);
  thr[g] = md[KNBR - 1];
}

// ---------------------------------------------------------------------------
// Kernel 3: collect (pass 2). Re-scan; only d2 <= thr enters the guarded
// insertDI. Writes per-(query,quarter) sorted (d, batch-local j) top-8.
// qd2 aliases qd (collect never reads qd). Exactness: {d2<=thr} contains the
// top-8 set incl. ties; ascending-j strict-< insertion matches reference.
// ---------------------------------------------------------------------------
__global__ __launch_bounds__(512) void knn_collect(
    const float* __restrict__ coords, const float* __restrict__ thr,
    float* __restrict__ qd2, int* __restrict__ qj2) {
  __shared__ float pd[SUBW][QPB][KNBR + 1];        // stride-9 pad
  __shared__ int   pi[SUBW][QPB][KNBR + 1];
  const int blk = blockIdx.x;
  const int b = blk >> 8;
  const int chunk = (blk >> 2) & 63;
  const int quarter = blk & 3;
  const int qi  = threadIdx.x & 63;
  const int sub = threadIdx.x >> 6;
  const int iq  = chunk * 64 + qi;
  const float* cb = coords + (size_t)b * NN * 3;
  const float qx = cb[iq * 3 + 0], qy = cb[iq * 3 + 1], qz = cb[iq * 3 + 2];
  const float tq = thr[b * NN + iq];
  float bd[KNBR];
  int bi[KNBR];
#pragma unroll
  for (int k = 0; k < KNBR; k++) { bd[k] = 3.0e38f; bi[k] = 0; }
  const int j0 = quarter * (NN / NQRT) + sub * 128;
  const float* cp = cb + (size_t)j0 * 3;
#pragma unroll 2
  for (int it = 0; it < 128; ++it) {
    int jj = j0 + it;
    float dx = cp[it * 3 + 0] - qx;
    float dy = cp[it * 3 + 1] - qy;
    float dz = cp[it * 3 + 2] - qz;
    float d2 = dx * dx + dy * dy + dz * dz;
    d2 = (jj == iq) ? 3.0e38f : d2;
    if (d2 <= tq) insertDI(d2, jj, bd, bi);   // rare path
  }
#pragma unroll
  for (int k = 0; k < KNBR; k++) {
    pd[sub][qi][k] = bd[k];
    pi[sub][qi][k] = bi[k];
  }
  __syncthreads();
  if (threadIdx.x < 64) {
    float md[KNBR];
    int mi[KNBR];
#pragma unroll
    for (int k = 0; k < KNBR; k++) { md[k] = 3.0e38f; mi[k] = 0; }
    for (int s = 0; s < SUBW; s++) {
#pragma unroll
      for (int k = 0; k < KNBR; k++) {
        float vd = pd[s][qi][k];
        if (vd < md[KNBR - 1]) insertDI(vd, pi[s][qi][k], md, mi);
      }
    }
    size_t base = ((size_t)(b * NN + iq) * NQRT + quarter) * KNBR;
#pragma unroll
    for (int k = 0; k < KNBR; k++) {
      qd2[base + k] = md[k];
      qj2[base + k] = mi[k];   // batch-local index (sentinel = (3e38, 0))
    }
  }
}

// ---------------------------------------------------------------------------
// Kernel 4: merge-fold + gather + moments + fused weights + output.
// One wave per node; 4 nodes/block.
//
// Merge fold (replaces knn_merge): lanes 0..31 hold the 4 per-quarter sorted
// (d, j) 8-lists. Exact rank by lex (d, j, lane): quarters are ascending-j
// ranges and within-quarter ties are ascending-j, so (d, j) reproduces the
// reference stable top_k tie-break; the lane term only disambiguates the
// (3e38, 0) sentinels, which always rank >= 8 (each query has >= 8 real
// neighbors passing the threshold). Exactly 8 lanes get rank < 8.
//
// NO LDS feature staging: the consuming pattern (fr[u], fr[64+3u..],
// fr[160+5u..]) is already lane-contiguous, so load straight from global.
// LDS drops 38400 -> ~7.6 KB: 8 blocks/CU (32 waves) instead of 4.
//
// Moments per node (432 floats in LDS):
//   S1[32] @0 | Z0[64][3] @32 | P[32][5] @224 | Q[16][3] @384
// ---------------------------------------------------------------------------
__global__ __launch_bounds__(256, 8) void msg_kernel(
    const float* __restrict__ feats, const float* __restrict__ coords,
    const float* __restrict__ qd2, const int* __restrict__ qj2,
    const float* __restrict__ Wf, float* __restrict__ out) {
  __shared__ float accb[4][432];
  __shared__ float sev[4][KNBR][3];
  __shared__ int snb[4][KNBR];

  const int w = threadIdx.x >> 6;   // wave within block -> node slot
  const int u = threadIdx.x & 63;   // lane
  const int node = blockIdx.x * 4 + w;
  const int b = node >> 12;

  // ---- folded knn_merge: all-pairs rank select over 32 (d, j) pairs
  float dmy = 3.0e38f;
  int jmy = 0x7FFFFFFF;
  if (u < 32) {
    dmy = qd2[(size_t)node * 32 + u];
    jmy = qj2[(size_t)node * 32 + u];
  }
  int rank = 0;
#pragma unroll
  for (int m = 0; m < 32; m++) {
    float dm = __shfl(dmy, m);      // uniform m -> v_readlane
    int jm = __shfl(jmy, m);
    bool less = (dm < dmy) ||
                (dm == dmy && (jm < jmy || (jm == jmy && m < u)));
    rank += less ? 1 : 0;
  }
  if (u < 32 && rank < KNBR) {
    int jg = b * NN + jmy;          // batch-local -> global node id
    snb[w][rank] = jg;
    sev[w][rank][0] = coords[(size_t)jg * 3 + 0] - coords[(size_t)node * 3 + 0];
    sev[w][rank][1] = coords[(size_t)jg * 3 + 1] - coords[(size_t)node * 3 + 1];
    sev[w][rank][2] = coords[(size_t)jg * 3 + 2] - coords[(size_t)node * 3 + 2];
  }
  __syncthreads();

  const float S_ = 0.31622776601683794f;  // 1/sqrt(10)
  const float T_ = 0.18257418583505536f;  // 1/sqrt(30)

  float z0x = 0.f, z0y = 0.f, z0z = 0.f;
  float s1 = 0.f, p0 = 0.f, p1 = 0.f, p2 = 0.f, p3 = 0.f, p4 = 0.f;
  float q0 = 0.f, q1 = 0.f, q2 = 0.f;

#pragma unroll
  for (int e = 0; e < KNBR; e++) {
    float X = sev[w][e][0], Y = sev[w][e][1], Z = sev[w][e][2];
    float sxv = S_ * X, syv = S_ * Y, szv = S_ * Z;
    float txv = T_ * X, tyv = T_ * Y, t2z = 2.f * T_ * Z;
    const float* fr = feats + (size_t)snb[w][e] * DF;   // direct global
    float x0v = fr[u];
    z0x += x0v * X;
    z0y += x0v * Y;
    z0z += x0v * Z;
    if (u < 32) {
      float a0 = fr[64 + 3 * u], a1 = fr[65 + 3 * u], a2 = fr[66 + 3 * u];
      s1 += a0 * X + a1 * Y + a2 * Z;
      p0 += a0 * syv + a1 * sxv;
      p1 += a0 * szv + a2 * sxv;
      p2 += a1 * szv + a2 * syv;
      p3 += a0 * sxv - a1 * syv;
      p4 += a2 * t2z - a0 * txv - a1 * tyv;
      if (u < 16) {
        float b0 = fr[160 + 5 * u], b1 = fr[161 + 5 * u], b2 = fr[162 + 5 * u];
        float b3 = fr[163 + 5 * u], b4 = fr[164 + 5 * u];
        q0 += b0 * syv + b1 * szv + b3 * sxv - b4 * txv;
        q1 += b0 * sxv + b2 * szv - b3 * syv - b4 * tyv;
        q2 += b1 * sxv + b2 * syv + b4 * t2z;
      }
    }
  }

  float* A = accb[w];
  A[32 + 3 * u + 0] = z0x;
  A[32 + 3 * u + 1] = z0y;
  A[32 + 3 * u + 2] = z0z;
  if (u < 32) {
    A[u] = s1;
    float* pp = A + 224 + 5 * u;
    pp[0] = p0; pp[1] = p1; pp[2] = p2; pp[3] = p3; pp[4] = p4;
  }
  if (u < 16) {
    float* qq = A + 384 + 3 * u;
    qq[0] = q0; qq[1] = q1; qq[2] = q2;
  }
  __syncthreads();

  const float* WA = Wf;          // 32x64
  const float* WB = Wf + 2048;   // 64x32
  const float* WC = Wf + 4096;   // 16x32
  const float* WD = Wf + 4608;   // 32x16
  float* orow = out + (size_t)node * DF;

  // y0[u] = sum_m S1[m] * WA[m][u]
  {
    float a = 0.f;
#pragma unroll
    for (int m = 0; m < 32; m++) a += A[m] * WA[m * 64 + u];
    orow[u] = a;
  }
  // y1 flat [w1*3+k], 96 outputs (two passes over 64 lanes)
#pragma unroll
  for (int m0 = 0; m0 < 96; m0 += 64) {
    int m = m0 + u;
    if (m < 96) {
      int w1 = m / 3, k = m - w1 * 3;
      float a = 0.f;
#pragma unroll
      for (int t = 0; t < 64; t++) a += A[32 + 3 * t + k] * WB[t * 32 + w1];
#pragma unroll
      for (int t = 0; t < 16; t++) a += A[384 + 3 * t + k] * WC[t * 32 + w1];
      orow[64 + m] = a;
    }
  }
  // y2 flat [w2*5+k], 80 outputs (two passes over 64 lanes)
#pragma unroll
  for (int m0 = 0; m0 < 80; m0 += 64) {
    int m = m0 + u;
    if (m < 80) {
      int w2 = m / 5, k = m - w2 * 5;
      float a = 0.f;
#pragma unroll
      for (int t = 0; t < 32; t++) a += A[224 + 5 * t + k] * WD[t * 16 + w2];
      orow[160 + m] = a;
    }
  }
}

// ---------------------------------------------------------------------------
extern "C" void kernel_launch(void* const* d_in, const int* in_sizes, int n_in,
                              void* d_out, int out_size, void* d_ws,
                              size_t ws_size, hipStream_t stream) {
  const float* feats  = (const float*)d_in[0];
  const float* coords = (const float*)d_in[1];
  const float* W1 = (const float*)d_in[2];
  const float* W2 = (const float*)d_in[3];
  const float* W3 = (const float*)d_in[4];
  const float* W4 = (const float*)d_in[5];
  const float* L0 = (const float*)d_in[6];
  const float* L1 = (const float*)d_in[7];
  const float* L2 = (const float*)d_in[8];
  float* out = (float*)d_out;

  // workspace (floats): Wf[5120] | qd[524288] (reused as qd2) | thr[16384]
  //                     | qj2[524288 i]   -> ~4.3 MB total
  float* Wf  = (float*)d_ws;
  float* qd  = (float*)d_ws + 5120;
  float* thr = (float*)d_ws + 5120 + 524288;
  int*   qj2 = (int*)((float*)d_ws + 5120 + 524288 + 16384);

  knn_scan_fuse<<<1034, 512, 0, stream>>>(coords, qd, W1, W2, W3, W4, L0, L1,
                                          L2, Wf);
  knn_thr<<<64, 256, 0, stream>>>(qd, thr);
  knn_collect<<<1024, 512, 0, stream>>>(coords, thr, qd, qj2);  // qd2 = qd
  msg_kernel<<<4096, 256, 0, stream>>>(feats, coords, qd, qj2, Wf, out);
}

// Round 3
// 215.526 us; speedup vs baseline: 1.0927x; 1.0927x over previous
//
#include <hip/hip_runtime.h>

#define NN   4096
#define KNBR 8
#define DF   240
#define SUBW 8    // candidate sub-ranges (waves) per kNN block
#define QPB  64   // queries per kNN block
#define NQRT 4    // candidate quarters

// Distance-only sorted-top-8 insert: pure med3/min chain, NO masks, NO bools.
__device__ __forceinline__ void insD(float v, float t[KNBR]) {
#pragma unroll
  for (int k = KNBR - 1; k >= 1; k--)
    t[k] = __builtin_amdgcn_fmed3f(t[k - 1], t[k], v);
  t[0] = fminf(t[0], v);
}

// (distance,index) sorted-top-8 insert — proven formulation (VGPR 24):
__device__ __forceinline__ void insertDI(float d2, int j, float bd[KNBR],
                                         int bi[KNBR]) {
#pragma unroll
  for (int k = KNBR - 1; k >= 1; k--) {
    bool mk  = d2 < bd[k];
    bool mk1 = d2 < bd[k - 1];
    bd[k] = mk ? (mk1 ? bd[k - 1] : d2) : bd[k];
    bi[k] = mk ? (mk1 ? bi[k - 1] : j) : bi[k];
  }
  bool m0 = d2 < bd[0];
  bd[0] = m0 ? d2 : bd[0];
  bi[0] = m0 ? j : bi[0];
}

// ---------------------------------------------------------------------------
// Kernel 1: kNN distance scan (pass 1) ⊕ weight fusion.
//   blocks [0,1024): per-(query,quarter) sorted top-8 DISTANCES -> qd.
//   blocks [1024,1034): fuse weights (5120 outputs, 512 threads/block):
//     WA = sA*(W2@L0) 32x64 | WB = sB*(W1@L1) 64x32
//     WC = sC*(W4@L1) 16x32 | WD = sD*(W3@L2) 32x16
// ---------------------------------------------------------------------------
__global__ __launch_bounds__(512) void knn_scan_fuse(
    const float* __restrict__ coords, float* __restrict__ qd,
    const float* __restrict__ W1, const float* __restrict__ W2,
    const float* __restrict__ W3, const float* __restrict__ W4,
    const float* __restrict__ L0, const float* __restrict__ L1,
    const float* __restrict__ L2, float* __restrict__ Wf) {
  if (blockIdx.x >= 1024) {            // -------- weight-fusion blocks
    const float sA = 0.012757759076995719f;  // sqrt(1/96)/8
    const float sB = 0.019764235376052370f;  // 1/sqrt(80*32)
    const float sC = 0.034232659844072875f;  // sqrt(3)/sqrt(80*32)
    const float sD = 0.098821176880261850f;  // sqrt(5/32)/4
    int idx = (blockIdx.x - 1024) * 512 + threadIdx.x;  // [0,5120)
    if (idx < 2048) {                       // WA: W2(32x64) @ L0(64x64)
      int u = idx >> 6, c = idx & 63;
      float a = 0.f;
#pragma unroll 8
      for (int m = 0; m < 64; m++) a += W2[u * 64 + m] * L0[m * 64 + c];
      Wf[idx] = sA * a;
    } else if (idx < 4096) {                // WB: W1(64x32) @ L1(32x32)
      int t = idx - 2048;
      int u = t >> 5, c = t & 31;
      float a = 0.f;
#pragma unroll 8
      for (int m = 0; m < 32; m++) a += W1[u * 32 + m] * L1[m * 32 + c];
      Wf[idx] = sB * a;
    } else if (idx < 4608) {                // WC: W4(16x32) @ L1(32x32)
      int t = idx - 4096;
      int u = t >> 5, c = t & 31;
      float a = 0.f;
#pragma unroll 8
      for (int m = 0; m < 32; m++) a += W4[u * 32 + m] * L1[m * 32 + c];
      Wf[idx] = sC * a;
    } else {                                // WD: W3(32x16) @ L2(16x16)
      int t = idx - 4608;
      int u = t >> 4, c = t & 15;
      float a = 0.f;
#pragma unroll 8
      for (int m = 0; m < 16; m++) a += W3[u * 16 + m] * L2[m * 16 + c];
      Wf[idx] = sD * a;
    }
    return;
  }

  // -------- distance-scan blocks (unchanged, verified hot loop)
  __shared__ float pd[SUBW][QPB][KNBR + 1];        // stride-9 pad
  const int blk = blockIdx.x;
  const int b = blk >> 8;
  const int chunk = (blk >> 2) & 63;
  const int quarter = blk & 3;
  const int qi  = threadIdx.x & 63;
  const int sub = threadIdx.x >> 6;
  const int iq  = chunk * 64 + qi;
  const float* cb = coords + (size_t)b * NN * 3;
  const float qx = cb[iq * 3 + 0], qy = cb[iq * 3 + 1], qz = cb[iq * 3 + 2];
  float td[KNBR];
#pragma unroll
  for (int k = 0; k < KNBR; k++) td[k] = 3.0e38f;
  const int j0 = quarter * (NN / NQRT) + sub * 128;
  const float* cp = cb + (size_t)j0 * 3;
#pragma unroll 4
  for (int it = 0; it < 128; ++it) {
    float dx = cp[it * 3 + 0] - qx;
    float dy = cp[it * 3 + 1] - qy;
    float dz = cp[it * 3 + 2] - qz;
    float d2 = dx * dx + dy * dy + dz * dz;
    d2 = (j0 + it == iq) ? 3.0e38f : d2;   // exclude self
    insD(d2, td);
  }
#pragma unroll
  for (int k = 0; k < KNBR; k++) pd[sub][qi][k] = td[k];
  __syncthreads();
  if (threadIdx.x < 64) {
    float md[KNBR];
#pragma unroll
    for (int k = 0; k < KNBR; k++) md[k] = 3.0e38f;
    for (int s = 0; s < SUBW; s++) {
#pragma unroll
      for (int k = 0; k < KNBR; k++) insD(pd[s][qi][k], md);
    }
    size_t base = ((size_t)(b * NN + iq) * NQRT + quarter) * KNBR;
#pragma unroll
    for (int k = 0; k < KNBR; k++) qd[base + k] = md[k];
  }
}

// ---------------------------------------------------------------------------
// Kernel 2: per-query threshold = global 8th-smallest distance.
// ---------------------------------------------------------------------------
__global__ __launch_bounds__(256) void knn_thr(
    const float* __restrict__ qd, float* __restrict__ thr) {
  int g = blockIdx.x * 256 + threadIdx.x;   // global query id
  float md[KNBR];
#pragma unroll
  for (int k = 0; k < KNBR; k++) md[k] = 3.0e38f;
  size_t base = (size_t)g * NQRT * KNBR;
#pragma unroll
  for (int i = 0; i < NQRT * KNBR; i++) insD(qd[base + i], md);
  thr[g] = md[KNBR - 1];
}

// ---------------------------------------------------------------------------
// Kernel 3: collect (pass 2). Re-scan; only d2 <= thr enters the guarded
// insertDI. Writes per-(query,quarter) sorted (d, batch-local j) top-8.
// qd2 aliases qd (collect never reads qd). Exactness: {d2<=thr} contains the
// top-8 set incl. ties; ascending-j strict-< insertion matches reference.
// ---------------------------------------------------------------------------
__global__ __launch_bounds__(512) void knn_collect(
    const float* __restrict__ coords, const float* __restrict__ thr,
    float* __restrict__ qd2, int* __restrict__ qj2) {
  __shared__ float pd[SUBW][QPB][KNBR + 1];        // stride-9 pad
  __shared__ int   pi[SUBW][QPB][KNBR + 1];
  const int blk = blockIdx.x;
  const int b = blk >> 8;
  const int chunk = (blk >> 2) & 63;
  const int quarter = blk & 3;
  const int qi  = threadIdx.x & 63;
  const int sub = threadIdx.x >> 6;
  const int iq  = chunk * 64 + qi;
  const float* cb = coords + (size_t)b * NN * 3;
  const float qx = cb[iq * 3 + 0], qy = cb[iq * 3 + 1], qz = cb[iq * 3 + 2];
  const float tq = thr[b * NN + iq];
  float bd[KNBR];
  int bi[KNBR];
#pragma unroll
  for (int k = 0; k < KNBR; k++) { bd[k] = 3.0e38f; bi[k] = 0; }
  const int j0 = quarter * (NN / NQRT) + sub * 128;
  const float* cp = cb + (size_t)j0 * 3;
#pragma unroll 2
  for (int it = 0; it < 128; ++it) {
    int jj = j0 + it;
    float dx = cp[it * 3 + 0] - qx;
    float dy = cp[it * 3 + 1] - qy;
    float dz = cp[it * 3 + 2] - qz;
    float d2 = dx * dx + dy * dy + dz * dz;
    d2 = (jj == iq) ? 3.0e38f : d2;
    if (d2 <= tq) insertDI(d2, jj, bd, bi);   // rare path
  }
#pragma unroll
  for (int k = 0; k < KNBR; k++) {
    pd[sub][qi][k] = bd[k];
    pi[sub][qi][k] = bi[k];
  }
  __syncthreads();
  if (threadIdx.x < 64) {
    float md[KNBR];
    int mi[KNBR];
#pragma unroll
    for (int k = 0; k < KNBR; k++) { md[k] = 3.0e38f; mi[k] = 0; }
    for (int s = 0; s < SUBW; s++) {
#pragma unroll
      for (int k = 0; k < KNBR; k++) {
        float vd = pd[s][qi][k];
        if (vd < md[KNBR - 1]) insertDI(vd, pi[s][qi][k], md, mi);
      }
    }
    size_t base = ((size_t)(b * NN + iq) * NQRT + quarter) * KNBR;
#pragma unroll
    for (int k = 0; k < KNBR; k++) {
      qd2[base + k] = md[k];
      qj2[base + k] = mi[k];   // batch-local index (sentinel = (3e38, 0))
    }
  }
}

// ---------------------------------------------------------------------------
// Kernel 4: merge-fold + gather + moments + fused weights + output.
// One wave per node; 4 nodes/block.
//
// __launch_bounds__(256, 4): VGPR cap 128. Round-2 post-mortem: (256, 8)
// forced VGPR<=64 -> scratch spills (WRITE_SIZE 15.4->113.8 MB, the +39 us
// regression). Cap 128 removes spill pressure; compiler lands ~60 VGPR,
// which still yields 8 blocks/CU if <=64.
//
// XCD-aware chunked swizzle (T1): kNN neighbors are spatially local node
// rows; chunked mapping gives each XCD a contiguous ~2 MB feats slab that
// fits its 4 MB L2 (round-robin scatters the full 15.7 MB across all 8).
// Bijective: grid 4096 % 8 == 0.
//
// Merge fold: lanes 0..31 hold the 4 per-quarter sorted (d, j) 8-lists.
// Exact rank by lex (d, j, lane): quarters are ascending-j ranges and
// within-quarter ties are ascending-j, so (d, j) reproduces the reference
// stable top_k tie-break; the lane term only disambiguates (3e38, 0)
// sentinels, which always rank >= 8. Exactly 8 lanes get rank < 8.
//
// Moments per node (432 floats in LDS):
//   S1[32] @0 | Z0[64][3] @32 | P[32][5] @224 | Q[16][3] @384
// ---------------------------------------------------------------------------
__global__ __launch_bounds__(256, 4) void msg_kernel(
    const float* __restrict__ feats, const float* __restrict__ coords,
    const float* __restrict__ qd2, const int* __restrict__ qj2,
    const float* __restrict__ Wf, float* __restrict__ out) {
  __shared__ float accb[4][432];
  __shared__ float sev[4][KNBR][3];
  __shared__ int snb[4][KNBR];

  const int bid = ((blockIdx.x & 7) << 9) | (blockIdx.x >> 3);  // XCD chunks
  const int w = threadIdx.x >> 6;   // wave within block -> node slot
  const int u = threadIdx.x & 63;   // lane
  const int node = bid * 4 + w;
  const int b = node >> 12;

  // ---- folded knn_merge: all-pairs rank select over 32 (d, j) pairs
  float dmy = 3.0e38f;
  int jmy = 0x7FFFFFFF;
  if (u < 32) {
    dmy = qd2[(size_t)node * 32 + u];
    jmy = qj2[(size_t)node * 32 + u];
  }
  int rank = 0;
#pragma unroll
  for (int m = 0; m < 32; m++) {
    float dm = __shfl(dmy, m);      // uniform m -> v_readlane
    int jm = __shfl(jmy, m);
    bool less = (dm < dmy) ||
                (dm == dmy && (jm < jmy || (jm == jmy && m < u)));
    rank += less ? 1 : 0;
  }
  if (u < 32 && rank < KNBR) {
    int jg = b * NN + jmy;          // batch-local -> global node id
    snb[w][rank] = jg;
    sev[w][rank][0] = coords[(size_t)jg * 3 + 0] - coords[(size_t)node * 3 + 0];
    sev[w][rank][1] = coords[(size_t)jg * 3 + 1] - coords[(size_t)node * 3 + 1];
    sev[w][rank][2] = coords[(size_t)jg * 3 + 2] - coords[(size_t)node * 3 + 2];
  }
  __syncthreads();

  const float S_ = 0.31622776601683794f;  // 1/sqrt(10)
  const float T_ = 0.18257418583505536f;  // 1/sqrt(30)

  float z0x = 0.f, z0y = 0.f, z0z = 0.f;
  float s1 = 0.f, p0 = 0.f, p1 = 0.f, p2 = 0.f, p3 = 0.f, p4 = 0.f;
  float q0 = 0.f, q1 = 0.f, q2 = 0.f;

#pragma unroll
  for (int e = 0; e < KNBR; e++) {
    float X = sev[w][e][0], Y = sev[w][e][1], Z = sev[w][e][2];
    float sxv = S_ * X, syv = S_ * Y, szv = S_ * Z;
    float txv = T_ * X, tyv = T_ * Y, t2z = 2.f * T_ * Z;
    const float* fr = feats + (size_t)snb[w][e] * DF;   // direct global
    float x0v = fr[u];
    z0x += x0v * X;
    z0y += x0v * Y;
    z0z += x0v * Z;
    if (u < 32) {
      float a0 = fr[64 + 3 * u], a1 = fr[65 + 3 * u], a2 = fr[66 + 3 * u];
      s1 += a0 * X + a1 * Y + a2 * Z;
      p0 += a0 * syv + a1 * sxv;
      p1 += a0 * szv + a2 * sxv;
      p2 += a1 * szv + a2 * syv;
      p3 += a0 * sxv - a1 * syv;
      p4 += a2 * t2z - a0 * txv - a1 * tyv;
      if (u < 16) {
        float b0 = fr[160 + 5 * u], b1 = fr[161 + 5 * u], b2 = fr[162 + 5 * u];
        float b3 = fr[163 + 5 * u], b4 = fr[164 + 5 * u];
        q0 += b0 * syv + b1 * szv + b3 * sxv - b4 * txv;
        q1 += b0 * sxv + b2 * szv - b3 * syv - b4 * tyv;
        q2 += b1 * sxv + b2 * syv + b4 * t2z;
      }
    }
  }

  float* A = accb[w];
  A[32 + 3 * u + 0] = z0x;
  A[32 + 3 * u + 1] = z0y;
  A[32 + 3 * u + 2] = z0z;
  if (u < 32) {
    A[u] = s1;
    float* pp = A + 224 + 5 * u;
    pp[0] = p0; pp[1] = p1; pp[2] = p2; pp[3] = p3; pp[4] = p4;
  }
  if (u < 16) {
    float* qq = A + 384 + 3 * u;
    qq[0] = q0; qq[1] = q1; qq[2] = q2;
  }
  __syncthreads();

  const float* WA = Wf;          // 32x64
  const float* WB = Wf + 2048;   // 64x32
  const float* WC = Wf + 4096;   // 16x32
  const float* WD = Wf + 4608;   // 32x16
  float* orow = out + (size_t)node * DF;

  // y0[u] = sum_m S1[m] * WA[m][u]
  {
    float a = 0.f;
#pragma unroll
    for (int m = 0; m < 32; m++) a += A[m] * WA[m * 64 + u];
    orow[u] = a;
  }
  // y1 flat [w1*3+k], 96 outputs (two passes over 64 lanes)
#pragma unroll
  for (int m0 = 0; m0 < 96; m0 += 64) {
    int m = m0 + u;
    if (m < 96) {
      int w1 = m / 3, k = m - w1 * 3;
      float a = 0.f;
#pragma unroll
      for (int t = 0; t < 64; t++) a += A[32 + 3 * t + k] * WB[t * 32 + w1];
#pragma unroll
      for (int t = 0; t < 16; t++) a += A[384 + 3 * t + k] * WC[t * 32 + w1];
      orow[64 + m] = a;
    }
  }
  // y2 flat [w2*5+k], 80 outputs (two passes over 64 lanes)
#pragma unroll
  for (int m0 = 0; m0 < 80; m0 += 64) {
    int m = m0 + u;
    if (m < 80) {
      int w2 = m / 5, k = m - w2 * 5;
      float a = 0.f;
#pragma unroll
      for (int t = 0; t < 32; t++) a += A[224 + 5 * t + k] * WD[t * 16 + w2];
      orow[160 + m] = a;
    }
  }
}

// ---------------------------------------------------------------------------
extern "C" void kernel_launch(void* const* d_in, const int* in_sizes, int n_in,
                              void* d_out, int out_size, void* d_ws,
                              size_t ws_size, hipStream_t stream) {
  const float* feats  = (const float*)d_in[0];
  const float* coords = (const float*)d_in[1];
  const float* W1 = (const float*)d_in[2];
  const float* W2 = (const float*)d_in[3];
  const float* W3 = (const float*)d_in[4];
  const float* W4 = (const float*)d_in[5];
  const float* L0 = (const float*)d_in[6];
  const float* L1 = (const float*)d_in[7];
  const float* L2 = (const float*)d_in[8];
  float* out = (float*)d_out;

  // workspace (floats): Wf[5120] | qd[524288] (reused as qd2) | thr[16384]
  //                     | qj2[524288 i]   -> ~4.3 MB total
  float* Wf  = (float*)d_ws;
  float* qd  = (float*)d_ws + 5120;
  float* thr = (float*)d_ws + 5120 + 524288;
  int*   qj2 = (int*)((float*)d_ws + 5120 + 524288 + 16384);

  knn_scan_fuse<<<1034, 512, 0, stream>>>(coords, qd, W1, W2, W3, W4, L0, L1,
                                          L2, Wf);
  knn_thr<<<64, 256, 0, stream>>>(qd, thr);
  knn_collect<<<1024, 512, 0, stream>>>(coords, thr, qd, qj2);  // qd2 = qd
  msg_kernel<<<4096, 256, 0, stream>>>(feats, coords, qd, qj2, Wf, out);
}

// Round 4
// 208.339 us; speedup vs baseline: 1.1304x; 1.0345x over previous
//
#include <hip/hip_runtime.h>

#define NN   4096
#define KNBR 8
#define DF   240
#define SUBW 8    // candidate sub-ranges (waves) per kNN block
#define QPB  64   // queries per kNN block
#define NQRT 4    // candidate quarters

// Distance-only sorted-top-8 insert: pure med3/min chain, NO masks, NO bools.
__device__ __forceinline__ void insD(float v, float t[KNBR]) {
#pragma unroll
  for (int k = KNBR - 1; k >= 1; k--)
    t[k] = __builtin_amdgcn_fmed3f(t[k - 1], t[k], v);
  t[0] = fminf(t[0], v);
}

// (distance,index) sorted-top-8 insert — proven formulation (VGPR 24):
__device__ __forceinline__ void insertDI(float d2, int j, float bd[KNBR],
                                         int bi[KNBR]) {
#pragma unroll
  for (int k = KNBR - 1; k >= 1; k--) {
    bool mk  = d2 < bd[k];
    bool mk1 = d2 < bd[k - 1];
    bd[k] = mk ? (mk1 ? bd[k - 1] : d2) : bd[k];
    bi[k] = mk ? (mk1 ? bi[k - 1] : j) : bi[k];
  }
  bool m0 = d2 < bd[0];
  bd[0] = m0 ? d2 : bd[0];
  bi[0] = m0 ? j : bi[0];
}

// ---------------------------------------------------------------------------
// Kernel 1: kNN distance scan (pass 1) ⊕ weight fusion.
//   blocks [0,1024): per-(query,quarter) sorted top-8 DISTANCES -> qd.
//     R4: the 1024 candidate coords of this block's quarter (12 KB) are
//     staged to LDS cooperatively (coalesced float4); hot loop reads
//     wave-uniform LDS (broadcast) instead of per-iter global loads.
//   blocks [1024,1034): fuse weights (5120 outputs):
//     WA = sA*(W2@L0) 32x64 | WB = sB*(W1@L1) 64x32
//     WC = sC*(W4@L1) 16x32 | WD = sD*(W3@L2) 32x16
// ---------------------------------------------------------------------------
__global__ __launch_bounds__(512) void knn_scan_fuse(
    const float* __restrict__ coords, float* __restrict__ qd,
    const float* __restrict__ W1, const float* __restrict__ W2,
    const float* __restrict__ W3, const float* __restrict__ W4,
    const float* __restrict__ L0, const float* __restrict__ L1,
    const float* __restrict__ L2, float* __restrict__ Wf) {
  if (blockIdx.x >= 1024) {            // -------- weight-fusion blocks
    const float sA = 0.012757759076995719f;  // sqrt(1/96)/8
    const float sB = 0.019764235376052370f;  // 1/sqrt(80*32)
    const float sC = 0.034232659844072875f;  // sqrt(3)/sqrt(80*32)
    const float sD = 0.098821176880261850f;  // sqrt(5/32)/4
    int idx = (blockIdx.x - 1024) * 512 + threadIdx.x;  // [0,5120)
    if (idx < 2048) {                       // WA: W2(32x64) @ L0(64x64)
      int u = idx >> 6, c = idx & 63;
      float a = 0.f;
#pragma unroll 8
      for (int m = 0; m < 64; m++) a += W2[u * 64 + m] * L0[m * 64 + c];
      Wf[idx] = sA * a;
    } else if (idx < 4096) {                // WB: W1(64x32) @ L1(32x32)
      int t = idx - 2048;
      int u = t >> 5, c = t & 31;
      float a = 0.f;
#pragma unroll 8
      for (int m = 0; m < 32; m++) a += W1[u * 32 + m] * L1[m * 32 + c];
      Wf[idx] = sB * a;
    } else if (idx < 4608) {                // WC: W4(16x32) @ L1(32x32)
      int t = idx - 4096;
      int u = t >> 5, c = t & 31;
      float a = 0.f;
#pragma unroll 8
      for (int m = 0; m < 32; m++) a += W4[u * 32 + m] * L1[m * 32 + c];
      Wf[idx] = sC * a;
    } else {                                // WD: W3(32x16) @ L2(16x16)
      int t = idx - 4608;
      int u = t >> 4, c = t & 15;
      float a = 0.f;
#pragma unroll 8
      for (int m = 0; m < 16; m++) a += W3[u * 16 + m] * L2[m * 16 + c];
      Wf[idx] = sD * a;
    }
    return;
  }

  // -------- distance-scan blocks
  __shared__ float pd[SUBW][QPB][KNBR + 1];        // stride-9 pad
  __shared__ float cand[3 * (NN / NQRT)];          // 3072 f = 12 KB
  const int blk = blockIdx.x;
  const int b = blk >> 8;
  const int chunk = (blk >> 2) & 63;
  const int quarter = blk & 3;
  const int qi  = threadIdx.x & 63;
  const int sub = threadIdx.x >> 6;
  const int iq  = chunk * 64 + qi;
  const float* cb = coords + (size_t)b * NN * 3;

  // stage this quarter's 1024 candidate coords: 768 float4, coalesced
  {
    const float4* src = (const float4*)(cb + quarter * 3072);  // 16B aligned
    float4* dst = (float4*)cand;
    int t = threadIdx.x;
    dst[t] = src[t];
    if (t < 256) dst[512 + t] = src[512 + t];
  }
  const float qx = cb[iq * 3 + 0], qy = cb[iq * 3 + 1], qz = cb[iq * 3 + 2];
  __syncthreads();

  float td[KNBR];
#pragma unroll
  for (int k = 0; k < KNBR; k++) td[k] = 3.0e38f;
  const int j0 = quarter * (NN / NQRT) + sub * 128;
  const int c0 = sub * 128;
#pragma unroll 4
  for (int it = 0; it < 128; ++it) {
    float dx = cand[(c0 + it) * 3 + 0] - qx;
    float dy = cand[(c0 + it) * 3 + 1] - qy;
    float dz = cand[(c0 + it) * 3 + 2] - qz;
    float d2 = dx * dx + dy * dy + dz * dz;
    d2 = (j0 + it == iq) ? 3.0e38f : d2;   // exclude self
    insD(d2, td);
  }
#pragma unroll
  for (int k = 0; k < KNBR; k++) pd[sub][qi][k] = td[k];
  __syncthreads();
  if (threadIdx.x < 64) {
    float md[KNBR];
#pragma unroll
    for (int k = 0; k < KNBR; k++) md[k] = 3.0e38f;
    for (int s = 0; s < SUBW; s++) {
#pragma unroll
      for (int k = 0; k < KNBR; k++) insD(pd[s][qi][k], md);
    }
    size_t base = ((size_t)(b * NN + iq) * NQRT + quarter) * KNBR;
#pragma unroll
    for (int k = 0; k < KNBR; k++) qd[base + k] = md[k];
  }
}

// ---------------------------------------------------------------------------
// Kernel 2: per-query threshold = global 8th-smallest distance.
// ---------------------------------------------------------------------------
__global__ __launch_bounds__(256) void knn_thr(
    const float* __restrict__ qd, float* __restrict__ thr) {
  int g = blockIdx.x * 256 + threadIdx.x;   // global query id
  float md[KNBR];
#pragma unroll
  for (int k = 0; k < KNBR; k++) md[k] = 3.0e38f;
  size_t base = (size_t)g * NQRT * KNBR;
#pragma unroll
  for (int i = 0; i < NQRT * KNBR; i++) insD(qd[base + i], md);
  thr[g] = md[KNBR - 1];
}

// ---------------------------------------------------------------------------
// Kernel 3: collect (pass 2). Re-scan (candidates from LDS, same staging as
// pass 1); only d2 <= thr enters the guarded insertDI (~12.5% any-lane).
// Writes per-(query,quarter) sorted (d, batch-local j) top-8.
// qd2 aliases qd (collect never reads qd). Exactness: {d2<=thr} contains the
// top-8 set incl. ties; ascending-j strict-< insertion matches reference.
// ---------------------------------------------------------------------------
__global__ __launch_bounds__(512) void knn_collect(
    const float* __restrict__ coords, const float* __restrict__ thr,
    float* __restrict__ qd2, int* __restrict__ qj2) {
  __shared__ float pd[SUBW][QPB][KNBR + 1];        // stride-9 pad
  __shared__ int   pi[SUBW][QPB][KNBR + 1];
  __shared__ float cand[3 * (NN / NQRT)];          // 12 KB -> 49.2 KB total
  const int blk = blockIdx.x;
  const int b = blk >> 8;
  const int chunk = (blk >> 2) & 63;
  const int quarter = blk & 3;
  const int qi  = threadIdx.x & 63;
  const int sub = threadIdx.x >> 6;
  const int iq  = chunk * 64 + qi;
  const float* cb = coords + (size_t)b * NN * 3;

  {
    const float4* src = (const float4*)(cb + quarter * 3072);
    float4* dst = (float4*)cand;
    int t = threadIdx.x;
    dst[t] = src[t];
    if (t < 256) dst[512 + t] = src[512 + t];
  }
  const float qx = cb[iq * 3 + 0], qy = cb[iq * 3 + 1], qz = cb[iq * 3 + 2];
  const float tq = thr[b * NN + iq];
  __syncthreads();

  float bd[KNBR];
  int bi[KNBR];
#pragma unroll
  for (int k = 0; k < KNBR; k++) { bd[k] = 3.0e38f; bi[k] = 0; }
  const int j0 = quarter * (NN / NQRT) + sub * 128;
  const int c0 = sub * 128;
#pragma unroll 2
  for (int it = 0; it < 128; ++it) {
    int jj = j0 + it;
    float dx = cand[(c0 + it) * 3 + 0] - qx;
    float dy = cand[(c0 + it) * 3 + 1] - qy;
    float dz = cand[(c0 + it) * 3 + 2] - qz;
    float d2 = dx * dx + dy * dy + dz * dz;
    d2 = (jj == iq) ? 3.0e38f : d2;
    if (d2 <= tq) insertDI(d2, jj, bd, bi);   // rare path
  }
#pragma unroll
  for (int k = 0; k < KNBR; k++) {
    pd[sub][qi][k] = bd[k];
    pi[sub][qi][k] = bi[k];
  }
  __syncthreads();
  if (threadIdx.x < 64) {
    float md[KNBR];
    int mi[KNBR];
#pragma unroll
    for (int k = 0; k < KNBR; k++) { md[k] = 3.0e38f; mi[k] = 0; }
    for (int s = 0; s < SUBW; s++) {
#pragma unroll
      for (int k = 0; k < KNBR; k++) {
        float vd = pd[s][qi][k];
        if (vd < md[KNBR - 1]) insertDI(vd, pi[s][qi][k], md, mi);
      }
    }
    size_t base = ((size_t)(b * NN + iq) * NQRT + quarter) * KNBR;
#pragma unroll
    for (int k = 0; k < KNBR; k++) {
      qd2[base + k] = md[k];
      qj2[base + k] = mi[k];   // batch-local index (sentinel = (3e38, 0))
    }
  }
}

// ---------------------------------------------------------------------------
// Kernel 4: merge-fold + gather + moments + fused weights + output.
// One wave per node; 4 nodes/block.
//
// R4: chunked register prefetch for the gather. R3 post-mortem: direct
// per-e scalar loads serialized (VGPR=48, one ~250cy L2 latency per e,
// 8x per wave). Now neighbors are processed in 2 chunks of 4: all <=36
// loads of a chunk are issued before any FMA consumes them (latency paid
// 2x per wave). Arrays are only indexed inside fully-unrolled loops ->
// registers (rule #20). (256,4) cap 128 VGPR; spill tripwire: WRITE_SIZE.
//
// XCD-aware chunked swizzle (T1): each XCD gets a contiguous ~2 MB feats
// slab that fits its 4 MB L2. Bijective: grid 4096 % 8 == 0.
//
// Merge fold: lanes 0..31 hold the 4 per-quarter sorted (d, j) 8-lists.
// Exact rank by lex (d, j, lane): quarters are ascending-j ranges and
// within-quarter ties are ascending-j, so (d, j) reproduces the reference
// stable top_k tie-break; the lane term only disambiguates (3e38, 0)
// sentinels, which always rank >= 8. Exactly 8 lanes get rank < 8.
//
// Moments per node (432 floats in LDS):
//   S1[32] @0 | Z0[64][3] @32 | P[32][5] @224 | Q[16][3] @384
// ---------------------------------------------------------------------------
__global__ __launch_bounds__(256, 4) void msg_kernel(
    const float* __restrict__ feats, const float* __restrict__ coords,
    const float* __restrict__ qd2, const int* __restrict__ qj2,
    const float* __restrict__ Wf, float* __restrict__ out) {
  __shared__ float accb[4][432];
  __shared__ float sev[4][KNBR][3];
  __shared__ int snb[4][KNBR];

  const int bid = ((blockIdx.x & 7) << 9) | (blockIdx.x >> 3);  // XCD chunks
  const int w = threadIdx.x >> 6;   // wave within block -> node slot
  const int u = threadIdx.x & 63;   // lane
  const int node = bid * 4 + w;
  const int b = node >> 12;

  // ---- folded knn_merge: all-pairs rank select over 32 (d, j) pairs
  float dmy = 3.0e38f;
  int jmy = 0x7FFFFFFF;
  if (u < 32) {
    dmy = qd2[(size_t)node * 32 + u];
    jmy = qj2[(size_t)node * 32 + u];
  }
  int rank = 0;
#pragma unroll
  for (int m = 0; m < 32; m++) {
    float dm = __shfl(dmy, m);      // uniform m -> v_readlane
    int jm = __shfl(jmy, m);
    bool less = (dm < dmy) ||
                (dm == dmy && (jm < jmy || (jm == jmy && m < u)));
    rank += less ? 1 : 0;
  }
  if (u < 32 && rank < KNBR) {
    int jg = b * NN + jmy;          // batch-local -> global node id
    snb[w][rank] = jg;
    sev[w][rank][0] = coords[(size_t)jg * 3 + 0] - coords[(size_t)node * 3 + 0];
    sev[w][rank][1] = coords[(size_t)jg * 3 + 1] - coords[(size_t)node * 3 + 1];
    sev[w][rank][2] = coords[(size_t)jg * 3 + 2] - coords[(size_t)node * 3 + 2];
  }
  __syncthreads();

  const float S_ = 0.31622776601683794f;  // 1/sqrt(10)
  const float T_ = 0.18257418583505536f;  // 1/sqrt(30)

  float z0x = 0.f, z0y = 0.f, z0z = 0.f;
  float s1 = 0.f, p0 = 0.f, p1 = 0.f, p2 = 0.f, p3 = 0.f, p4 = 0.f;
  float q0 = 0.f, q1 = 0.f, q2 = 0.f;

#pragma unroll
  for (int h = 0; h < 2; h++) {
    // ---- prefetch chunk of 4 neighbor rows into registers (all loads
    //      issued before any consumer FMA)
    const float* fr[4];
    float xv[4], av0[4], av1[4], av2[4];
    float bv0[4], bv1[4], bv2[4], bv3[4], bv4[4];
#pragma unroll
    for (int i = 0; i < 4; i++) {
      fr[i] = feats + (size_t)snb[w][4 * h + i] * DF;
      xv[i] = fr[i][u];
    }
    if (u < 32) {
#pragma unroll
      for (int i = 0; i < 4; i++) {
        av0[i] = fr[i][64 + 3 * u];
        av1[i] = fr[i][65 + 3 * u];
        av2[i] = fr[i][66 + 3 * u];
      }
      if (u < 16) {
#pragma unroll
        for (int i = 0; i < 4; i++) {
          bv0[i] = fr[i][160 + 5 * u];
          bv1[i] = fr[i][161 + 5 * u];
          bv2[i] = fr[i][162 + 5 * u];
          bv3[i] = fr[i][163 + 5 * u];
          bv4[i] = fr[i][164 + 5 * u];
        }
      }
    }
    // ---- consume chunk
#pragma unroll
    for (int i = 0; i < 4; i++) {
      const int e = 4 * h + i;
      float X = sev[w][e][0], Y = sev[w][e][1], Z = sev[w][e][2];
      float sxv = S_ * X, syv = S_ * Y, szv = S_ * Z;
      float txv = T_ * X, tyv = T_ * Y, t2z = 2.f * T_ * Z;
      z0x += xv[i] * X;
      z0y += xv[i] * Y;
      z0z += xv[i] * Z;
      if (u < 32) {
        s1 += av0[i] * X + av1[i] * Y + av2[i] * Z;
        p0 += av0[i] * syv + av1[i] * sxv;
        p1 += av0[i] * szv + av2[i] * sxv;
        p2 += av1[i] * szv + av2[i] * syv;
        p3 += av0[i] * sxv - av1[i] * syv;
        p4 += av2[i] * t2z - av0[i] * txv - av1[i] * tyv;
        if (u < 16) {
          q0 += bv0[i] * syv + bv1[i] * szv + bv3[i] * sxv - bv4[i] * txv;
          q1 += bv0[i] * sxv + bv2[i] * szv - bv3[i] * syv - bv4[i] * tyv;
          q2 += bv1[i] * sxv + bv2[i] * syv + bv4[i] * t2z;
        }
      }
    }
  }

  float* A = accb[w];
  A[32 + 3 * u + 0] = z0x;
  A[32 + 3 * u + 1] = z0y;
  A[32 + 3 * u + 2] = z0z;
  if (u < 32) {
    A[u] = s1;
    float* pp = A + 224 + 5 * u;
    pp[0] = p0; pp[1] = p1; pp[2] = p2; pp[3] = p3; pp[4] = p4;
  }
  if (u < 16) {
    float* qq = A + 384 + 3 * u;
    qq[0] = q0; qq[1] = q1; qq[2] = q2;
  }
  __syncthreads();

  const float* WA = Wf;          // 32x64
  const float* WB = Wf + 2048;   // 64x32
  const float* WC = Wf + 4096;   // 16x32
  const float* WD = Wf + 4608;   // 32x16
  float* orow = out + (size_t)node * DF;

  // y0[u] = sum_m S1[m] * WA[m][u]
  {
    float a = 0.f;
#pragma unroll
    for (int m = 0; m < 32; m++) a += A[m] * WA[m * 64 + u];
    orow[u] = a;
  }
  // y1 flat [w1*3+k], 96 outputs (two passes over 64 lanes)
#pragma unroll
  for (int m0 = 0; m0 < 96; m0 += 64) {
    int m = m0 + u;
    if (m < 96) {
      int w1 = m / 3, k = m - w1 * 3;
      float a = 0.f;
#pragma unroll
      for (int t = 0; t < 64; t++) a += A[32 + 3 * t + k] * WB[t * 32 + w1];
#pragma unroll
      for (int t = 0; t < 16; t++) a += A[384 + 3 * t + k] * WC[t * 32 + w1];
      orow[64 + m] = a;
    }
  }
  // y2 flat [w2*5+k], 80 outputs (two passes over 64 lanes)
#pragma unroll
  for (int m0 = 0; m0 < 80; m0 += 64) {
    int m = m0 + u;
    if (m < 80) {
      int w2 = m / 5, k = m - w2 * 5;
      float a = 0.f;
#pragma unroll
      for (int t = 0; t < 32; t++) a += A[224 + 5 * t + k] * WD[t * 16 + w2];
      orow[160 + m] = a;
    }
  }
}

// ---------------------------------------------------------------------------
extern "C" void kernel_launch(void* const* d_in, const int* in_sizes, int n_in,
                              void* d_out, int out_size, void* d_ws,
                              size_t ws_size, hipStream_t stream) {
  const float* feats  = (const float*)d_in[0];
  const float* coords = (const float*)d_in[1];
  const float* W1 = (const float*)d_in[2];
  const float* W2 = (const float*)d_in[3];
  const float* W3 = (const float*)d_in[4];
  const float* W4 = (const float*)d_in[5];
  const float* L0 = (const float*)d_in[6];
  const float* L1 = (const float*)d_in[7];
  const float* L2 = (const float*)d_in[8];
  float* out = (float*)d_out;

  // workspace (floats): Wf[5120] | qd[524288] (reused as qd2) | thr[16384]
  //                     | qj2[524288 i]   -> ~4.3 MB total
  float* Wf  = (float*)d_ws;
  float* qd  = (float*)d_ws + 5120;
  float* thr = (float*)d_ws + 5120 + 524288;
  int*   qj2 = (int*)((float*)d_ws + 5120 + 524288 + 16384);

  knn_scan_fuse<<<1034, 512, 0, stream>>>(coords, qd, W1, W2, W3, W4, L0, L1,
                                          L2, Wf);
  knn_thr<<<64, 256, 0, stream>>>(qd, thr);
  knn_collect<<<1024, 512, 0, stream>>>(coords, thr, qd, qj2);  // qd2 = qd
  msg_kernel<<<4096, 256, 0, stream>>>(feats, coords, qd, qj2, Wf, out);
}